// Round 1
// baseline (376.445 us; speedup 1.0000x reference)
//
#include <hip/hip_runtime.h>
#include <hip/hip_bf16.h>

typedef unsigned short u16;
typedef __attribute__((ext_vector_type(8))) short  bf16x8;
typedef __attribute__((ext_vector_type(4))) float  fx4;

// flat offsets of TT cores in the packed kernel (reference iterates k=3..0 from idx 0)
#define OFF_C0 0       // core for k=3: [8 x 256]   core0[i4][a3*8+o4]
#define OFF_C1 2048    // core for k=2: [256 x 256] core1[i3*32+a3][a2*8+o3]
#define OFF_C2 67584   // core for k=1: [256 x 256] core2[i2*32+a2][a1*8+o2]
#define OFF_C3 133120  // core for k=0: [256 x 8]   core3[i1*32+a1][o1]

static __device__ __forceinline__ u16 f2bf(float f) {
  union { __hip_bfloat16 h; u16 u; } cv;
  cv.h = __float2bfloat16(f);
  return cv.u;
}

// W34[(i3,i4), (a2,o3,o4)] = sum_a3 core1[i3*32+a3, a2*8+o3] * core0[i4, a3*8+o4]
// shape 64 x 2048, fp32. 131072 threads.
__global__ void build_w34(const float* __restrict__ ker, float* __restrict__ w34) {
  int t = blockIdx.x * 256 + threadIdx.x;
  int r34 = t >> 11, c = t & 2047;
  int i3 = r34 >> 3, i4 = r34 & 7;
  int a2 = c >> 6, o3 = (c >> 3) & 7, o4 = c & 7;
  float s = 0.f;
#pragma unroll 8
  for (int a3 = 0; a3 < 32; ++a3) {
    float k1 = ker[OFF_C1 + (i3 * 32 + a3) * 256 + a2 * 8 + o3];
    float k0 = ker[OFF_C0 + i4 * 256 + a3 * 8 + o4];
    s += k1 * k0;
  }
  w34[t] = s;
}

// W234t[(a1,o2,o3,o4), (i2,i3,i4)] = sum_a2 core2[i2*32+a2, a1*8+o2] * W34[(i3,i4),(a2,o3,o4)]
// shape 16384 x 512, bf16. Thread computes 8 outputs (o4 = 0..7). 1048576 threads.
__global__ void build_w234t(const float* __restrict__ ker, const float* __restrict__ w34,
                            u16* __restrict__ w234t) {
  int t = blockIdx.x * 256 + threadIdx.x;
  int i234 = t & 511, cg = t >> 9;              // cg = a1*64 + o2*8 + o3
  int a1 = cg >> 6, o2 = (cg >> 3) & 7, o3 = cg & 7;
  int i2 = i234 >> 6, i34 = i234 & 63;
  float acc[8] = {0.f, 0.f, 0.f, 0.f, 0.f, 0.f, 0.f, 0.f};
  for (int a2 = 0; a2 < 32; ++a2) {
    float c2 = ker[OFF_C2 + (i2 * 32 + a2) * 256 + a1 * 8 + o2];
    const fx4* w = (const fx4*)(w34 + i34 * 2048 + a2 * 64 + o3 * 8);
    fx4 w0 = w[0], w1 = w[1];
#pragma unroll
    for (int q = 0; q < 4; ++q) acc[q]     += c2 * w0[q];
#pragma unroll
    for (int q = 0; q < 4; ++q) acc[4 + q] += c2 * w1[q];
  }
#pragma unroll
  for (int o4 = 0; o4 < 8; ++o4)
    w234t[(cg * 8 + o4) * 512 + i234] = f2bf(acc[o4]);
}

// Wt[j, i] = sum_a1 core3[i1*32+a1, o1] * W234t[a1*512 + j234, i234]
// shape 4096 x 4096 bf16 (transposed W, i.e. "B^T" for the GEMM).
// Thread computes 8 outputs (o1 = 0..7). 2097152 threads.
__global__ void build_wt(const float* __restrict__ ker, const u16* __restrict__ w234t,
                         u16* __restrict__ wt) {
  int t = blockIdx.x * 256 + threadIdx.x;
  int i = t & 4095, j234 = t >> 12;
  int i1 = i >> 9, i234 = i & 511;
  float acc[8] = {0.f, 0.f, 0.f, 0.f, 0.f, 0.f, 0.f, 0.f};
  for (int a1 = 0; a1 < 32; ++a1) {
    union { u16 u; __hip_bfloat16 h; } cv;
    cv.u = w234t[(a1 * 512 + j234) * 512 + i234];
    float w = __bfloat162float(cv.h);
    const float* c3 = ker + OFF_C3 + (i1 * 32 + a1) * 8;  // wave-uniform row of core3
#pragma unroll
    for (int o1 = 0; o1 < 8; ++o1) acc[o1] += c3[o1] * w;
  }
#pragma unroll
  for (int o1 = 0; o1 < 8; ++o1)
    wt[(size_t)(o1 * 512 + j234) * 4096 + i] = f2bf(acc[o1]);
}

// x (fp32) -> bf16, 8 elements/thread, 2097152 threads.
__global__ void x_to_bf16(const float* __restrict__ x, u16* __restrict__ xb) {
  int t = blockIdx.x * 256 + threadIdx.x;
  const fx4* p = (const fx4*)(x + (size_t)t * 8);
  fx4 v0 = p[0], v1 = p[1];
  u16 tmp[8];
#pragma unroll
  for (int q = 0; q < 4; ++q) tmp[q] = f2bf(v0[q]);
#pragma unroll
  for (int q = 0; q < 4; ++q) tmp[4 + q] = f2bf(v1[q]);
  typedef __attribute__((ext_vector_type(8))) u16 u16x8;
  *(u16x8*)(xb + (size_t)t * 8) = *(const u16x8*)tmp;
}

__device__ __forceinline__ void gld16(const u16* g, u16* l) {
  __builtin_amdgcn_global_load_lds((const __attribute__((address_space(1))) void*)g,
                                   (__attribute__((address_space(3))) void*)l, 16, 0, 0);
}

// C[M,N] = A[M,K](bf16, row-major) * Bt[N,K](bf16, row-major)^T + bias, fp32 out.
// 128x128 tile, BK=32, 4 waves (2x2), 4x4 16x16x32 MFMA fragments per wave (m97 structure).
__global__ __launch_bounds__(256) void gemm_bt(const u16* __restrict__ A, const u16* __restrict__ Bt,
                                               const float* __restrict__ bias, float* __restrict__ C) {
  __shared__ __align__(16) u16 As[128 * 32];  // [row][k] 64B rows
  __shared__ __align__(16) u16 Bs[128 * 32];

  const int tid = threadIdx.x;
  const int lane = tid & 63;
  const int wave = tid >> 6;
  const int wm = wave >> 1, wn = wave & 1;
  const int bm = blockIdx.y * 128, bn = blockIdx.x * 128;

  // staging: wave handles chunks 2w, 2w+1; chunk = 16 rows of the tile (1024B)
  const int rT = 2 * wave * 16 + (lane >> 2);       // tile row for chunk0
  const size_t gA0 = (size_t)(bm + rT) * 4096 + (lane & 3) * 8;
  const size_t gA1 = gA0 + (size_t)16 * 4096;
  const size_t gB0 = (size_t)(bn + rT) * 4096 + (lane & 3) * 8;
  const size_t gB1 = gB0 + (size_t)16 * 4096;
  u16* lA0 = As + 2 * wave * 512;  // wave-uniform LDS base; HW adds lane*16B
  u16* lA1 = lA0 + 512;
  u16* lB0 = Bs + 2 * wave * 512;
  u16* lB1 = lB0 + 512;

  const int fr = lane & 15, fg = lane >> 4;
  const u16* pa = As + (wm * 64 + fr) * 32 + fg * 8;
  const u16* pb = Bs + (wn * 64 + fr) * 32 + fg * 8;

  fx4 zero = {0.f, 0.f, 0.f, 0.f};
  fx4 acc[4][4];
#pragma unroll
  for (int mt = 0; mt < 4; ++mt)
#pragma unroll
    for (int nt = 0; nt < 4; ++nt) acc[mt][nt] = zero;

  for (int kt = 0; kt < 4096 / 32; ++kt) {
    const int k0 = kt * 32;
    gld16(A + gA0 + k0, lA0);
    gld16(A + gA1 + k0, lA1);
    gld16(Bt + gB0 + k0, lB0);
    gld16(Bt + gB1 + k0, lB1);
    __syncthreads();  // drains vmcnt before any wave reads LDS

    bf16x8 av[4], bv[4];
#pragma unroll
    for (int mt = 0; mt < 4; ++mt) av[mt] = *(const bf16x8*)(pa + mt * 512);
#pragma unroll
    for (int nt = 0; nt < 4; ++nt) bv[nt] = *(const bf16x8*)(pb + nt * 512);
#pragma unroll
    for (int mt = 0; mt < 4; ++mt)
#pragma unroll
      for (int nt = 0; nt < 4; ++nt)
        acc[mt][nt] = __builtin_amdgcn_mfma_f32_16x16x32_bf16(av[mt], bv[nt], acc[mt][nt], 0, 0, 0);
    __syncthreads();  // protect LDS from next iteration's staging
  }

  // C/D layout: col = lane&15, row = (lane>>4)*4 + reg  [m89]
  const int crow0 = bm + wm * 64 + fg * 4;
  const int ccol0 = bn + wn * 64 + fr;
#pragma unroll
  for (int nt = 0; nt < 4; ++nt) {
    const int col = ccol0 + nt * 16;
    const float bv = bias[col];
#pragma unroll
    for (int mt = 0; mt < 4; ++mt) {
      const int r0 = crow0 + mt * 16;
#pragma unroll
      for (int q = 0; q < 4; ++q)
        C[(size_t)(r0 + q) * 4096 + col] = acc[mt][nt][q] + bv;
    }
  }
}

extern "C" void kernel_launch(void* const* d_in, const int* in_sizes, int n_in,
                              void* d_out, int out_size, void* d_ws, size_t ws_size,
                              hipStream_t stream) {
  const float* x    = (const float*)d_in[0];
  const float* ker  = (const float*)d_in[1];
  const float* bias = (const float*)d_in[2];
  float* out = (float*)d_out;

  char* ws = (char*)d_ws;
  u16*  xb    = (u16*)ws;                      // 32 MB  bf16 x
  u16*  wt    = (u16*)(ws + 33554432);         // 32 MB  bf16 W^T
  u16*  w234t = (u16*)(ws + 67108864);         // 16 MB  bf16 W234^T
  float* w34  = (float*)(ws + 83886080);       // 512 KB fp32 W34
  // total ws use: 84,410,368 bytes

  build_w34  <<<512, 256, 0, stream>>>(ker, w34);
  build_w234t<<<4096, 256, 0, stream>>>(ker, w34, w234t);
  build_wt   <<<8192, 256, 0, stream>>>(ker, w234t, wt);
  x_to_bf16  <<<8192, 256, 0, stream>>>(x, xb);
  gemm_bt    <<<dim3(32, 32), 256, 0, stream>>>(xb, wt, bias, out);
}

// Round 2
// 180.379 us; speedup vs baseline: 2.0870x; 2.0870x over previous
//
#include <hip/hip_runtime.h>
#include <hip/hip_bf16.h>

typedef unsigned short u16;
typedef __attribute__((ext_vector_type(8))) short  bf16x8;
typedef __attribute__((ext_vector_type(4))) float  fx4;

// flat offsets of TT cores in the packed kernel (reference iterates k=3..0 from idx 0)
#define OFF_C0 0       // core for k=3: [8 x 256]   core0[i4][a3*8+o4]
#define OFF_C1 2048    // core for k=2: [256 x 256] core1[i3*32+a3][a2*8+o3]
#define OFF_C2 67584   // core for k=1: [256 x 256] core2[i2*32+a2][a1*8+o2]
#define OFF_C3 133120  // core for k=0: [256 x 8]   core3[i1*32+a1][o1]

static __device__ __forceinline__ u16 f2bf(float f) {
  union { __hip_bfloat16 h; u16 u; } cv;
  cv.h = __float2bfloat16(f);
  return cv.u;
}
static __device__ __forceinline__ float bf2f(u16 u) {
  union { u16 u; __hip_bfloat16 h; } cv;
  cv.u = u;
  return __bfloat162float(cv.h);
}

// W34T[c][i34], c = a2*64 + o3*8 + o4 (2048 x 64 fp32):
// W34T[c][i34] = sum_a3 core1[i3*32+a3, a2*8+o3] * core0[i4, a3*8+o4]
__global__ void build_w34T(const float* __restrict__ ker, float* __restrict__ w34T) {
  int t = blockIdx.x * 256 + threadIdx.x;   // 131072 threads
  int i34 = t & 63, c = t >> 6;
  int a2 = c >> 6, o3 = (c >> 3) & 7, o4 = c & 7;
  int i3 = i34 >> 3, i4 = i34 & 7;
  float s = 0.f;
#pragma unroll 8
  for (int a3 = 0; a3 < 32; ++a3) {
    float k1 = ker[OFF_C1 + (i3 * 32 + a3) * 256 + a2 * 8 + o3];
    float k0 = ker[OFF_C0 + i4 * 256 + a3 * 8 + o4];
    s += k1 * k0;
  }
  w34T[c * 64 + i34] = s;
}

// W234t[(a1*64+o2*8+o3)*8 + o4][i234] = sum_a2 core2[i2*32+a2, a1*8+o2] * W34T[a2*64+o3*8+o4][i34]
// thread owns (a1, o3, i234), computes 8x8 (o2, o4) outputs. 131072 threads.
__global__ void build_w234t2(const float* __restrict__ ker, const float* __restrict__ w34T,
                             u16* __restrict__ w234t) {
  int t = blockIdx.x * 256 + threadIdx.x;
  int i234 = t & 511, g = t >> 9;           // g = a1*8 + o3
  int a1 = g >> 3, o3 = g & 7;
  int i2 = i234 >> 6, i34 = i234 & 63;
  float acc[8][8];
#pragma unroll
  for (int a = 0; a < 8; ++a)
#pragma unroll
    for (int b = 0; b < 8; ++b) acc[a][b] = 0.f;
  for (int a2 = 0; a2 < 32; ++a2) {
    float w[8];
#pragma unroll
    for (int o4 = 0; o4 < 8; ++o4)
      w[o4] = w34T[(a2 * 64 + o3 * 8 + o4) * 64 + i34];   // lane-coalesced (i34 = lane-contig)
#pragma unroll
    for (int o2 = 0; o2 < 8; ++o2) {
      float c2 = ker[OFF_C2 + (i2 * 32 + a2) * 256 + a1 * 8 + o2];
#pragma unroll
      for (int o4 = 0; o4 < 8; ++o4) acc[o2][o4] += c2 * w[o4];
    }
  }
#pragma unroll
  for (int o2 = 0; o2 < 8; ++o2) {
    int cg = a1 * 64 + o2 * 8 + o3;
#pragma unroll
    for (int o4 = 0; o4 < 8; ++o4)
      w234t[(cg * 8 + o4) * 512 + i234] = f2bf(acc[o2][o4]);
  }
}

// Wt[j,i]: thread owns (j234, i234), reads each w234t element ONCE, computes all 64 (i1,o1).
// 262144 threads.
__global__ void build_wt2(const float* __restrict__ ker, const u16* __restrict__ w234t,
                          u16* __restrict__ wt) {
  int t = blockIdx.x * 256 + threadIdx.x;
  int i234 = t & 511, j234 = t >> 9;
  float acc[8][8];
#pragma unroll
  for (int a = 0; a < 8; ++a)
#pragma unroll
    for (int b = 0; b < 8; ++b) acc[a][b] = 0.f;
  for (int a1 = 0; a1 < 32; ++a1) {
    float w = bf2f(w234t[(a1 * 512 + j234) * 512 + i234]);  // coalesced, read-once
#pragma unroll
    for (int i1 = 0; i1 < 8; ++i1) {
      const float* c3 = ker + OFF_C3 + (i1 * 32 + a1) * 8;  // wave-uniform -> s_load
#pragma unroll
      for (int o1 = 0; o1 < 8; ++o1) acc[i1][o1] += c3[o1] * w;
    }
  }
#pragma unroll
  for (int o1 = 0; o1 < 8; ++o1)
#pragma unroll
    for (int i1 = 0; i1 < 8; ++i1)
      wt[(size_t)(o1 * 512 + j234) * 4096 + i1 * 512 + i234] = f2bf(acc[i1][o1]);
}

// x (fp32) -> bf16, 8 elements/thread, 2097152 threads.
__global__ void x_to_bf16(const float* __restrict__ x, u16* __restrict__ xb) {
  int t = blockIdx.x * 256 + threadIdx.x;
  const fx4* p = (const fx4*)(x + (size_t)t * 8);
  fx4 v0 = p[0], v1 = p[1];
  u16 tmp[8];
#pragma unroll
  for (int q = 0; q < 4; ++q) tmp[q] = f2bf(v0[q]);
#pragma unroll
  for (int q = 0; q < 4; ++q) tmp[4 + q] = f2bf(v1[q]);
  typedef __attribute__((ext_vector_type(8))) u16 u16x8;
  *(u16x8*)(xb + (size_t)t * 8) = *(const u16x8*)tmp;
}

__device__ __forceinline__ void gld16(const u16* g, u16* l) {
  __builtin_amdgcn_global_load_lds((const __attribute__((address_space(1))) void*)g,
                                   (__attribute__((address_space(3))) void*)l, 16, 0, 0);
}

// C[4096,4096] = A[4096,4096](bf16) * Bt[4096,4096](bf16)^T + bias, fp32 out.
// 256x256 tile, BK=32, 8 waves (2Mx4N), per-wave 128x64 out (8x4 frags of 16x16x32).
// 4 LDS buffers per operand (128 KiB), stage distance 3, counted vmcnt(8),
// raw s_barrier (no vmcnt(0) drain in loop), XOR slot swizzle (both-sides, rule #21).
__global__ __launch_bounds__(512, 2) void gemm_bt2(const u16* __restrict__ A, const u16* __restrict__ Bt,
                                                   const float* __restrict__ bias, float* __restrict__ C) {
  __shared__ __align__(16) u16 sh[65536];  // bytes: A bufs [0,64K), B bufs [64K,128K)

  const int tid = threadIdx.x;
  const int lane = tid & 63;
  const int wave = tid >> 6;
  const int wm = wave >> 2, wn = wave & 3;
  const int fr = lane & 15, fg = lane >> 4;

  // XCD-aware swizzle (256 blocks, 256%8==0 -> simple form valid)
  const int bid = blockIdx.x;
  const int wg = (bid & 7) * 32 + (bid >> 3);
  const int bm = (wg >> 4) * 256, bn = (wg & 15) * 256;

  // staging: thread -> row tid>>2 (+128 for 2nd load), slot tid&3; LDS dest linear (= tid*16B),
  // global source slot pre-swizzled: s ^ ((row>>1)&3)  (same for row and row+128)
  const int srow = tid >> 2;
  const int sco = (((tid & 3) ^ ((tid >> 3) & 3)) * 8);
  const size_t agA0 = (size_t)(bm + srow) * 4096 + sco;
  const size_t agA1 = agA0 + (size_t)128 * 4096;
  const size_t agB0 = (size_t)(bn + srow) * 4096 + sco;
  const size_t agB1 = agB0 + (size_t)128 * 4096;
  const int ldsW = wave * 512;  // elements

  fx4 acc[8][4];
#pragma unroll
  for (int m = 0; m < 8; ++m)
#pragma unroll
    for (int n = 0; n < 4; ++n) acc[m][n] = (fx4){0.f, 0.f, 0.f, 0.f};

  // prologue: stage tiles 0,1,2 (12 loads/thread); wait tile0 landed (drop oldest 4)
  for (int pt = 0; pt < 3; ++pt) {
    u16* Aq = sh + pt * 8192;
    u16* Bq = sh + 32768 + pt * 8192;
    gld16(A + agA0 + pt * 32, Aq + ldsW);
    gld16(A + agA1 + pt * 32, Aq + ldsW + 4096);
    gld16(Bt + agB0 + pt * 32, Bq + ldsW);
    gld16(Bt + agB1 + pt * 32, Bq + ldsW + 4096);
  }
  asm volatile("s_waitcnt vmcnt(8)" ::: "memory");
  __builtin_amdgcn_s_barrier();

  for (int t = 0; t < 128; ++t) {
    u16* Ap = sh + (t & 3) * 8192;
    u16* Bp = sh + 32768 + (t & 3) * 8192;
    u16* Aq = sh + ((t + 3) & 3) * 8192;
    u16* Bq = sh + 32768 + ((t + 3) & 3) * 8192;
    const size_t ko = (size_t)(((t + 3) & 127) * 32);  // wraparound tail: keeps vmcnt imm constant

    // ---- phase A: quadrant mh=0 ----
    bf16x8 av[4], bv[4];
#pragma unroll
    for (int m = 0; m < 4; ++m) {
      const int R = wm * 128 + m * 16 + fr;
      av[m] = *(const bf16x8*)(Ap + R * 32 + ((fg ^ ((R >> 1) & 3)) * 8));
    }
#pragma unroll
    for (int n = 0; n < 4; ++n) {
      const int R = wn * 64 + n * 16 + fr;
      bv[n] = *(const bf16x8*)(Bp + R * 32 + ((fg ^ ((R >> 1) & 3)) * 8));
    }
    gld16(A + agA0 + ko, Aq + ldsW);
    gld16(A + agA1 + ko, Aq + ldsW + 4096);
    __builtin_amdgcn_s_barrier();
    __builtin_amdgcn_s_setprio(1);
#pragma unroll
    for (int m = 0; m < 4; ++m)
#pragma unroll
      for (int n = 0; n < 4; ++n)
        acc[m][n] = __builtin_amdgcn_mfma_f32_16x16x32_bf16(av[m], bv[n], acc[m][n], 0, 0, 0);
    __builtin_amdgcn_s_setprio(0);
    __builtin_amdgcn_s_barrier();

    // ---- phase B: quadrant mh=1 (bv reused from registers) ----
    bf16x8 aw[4];
#pragma unroll
    for (int m = 0; m < 4; ++m) {
      const int R = wm * 128 + 64 + m * 16 + fr;
      aw[m] = *(const bf16x8*)(Ap + R * 32 + ((fg ^ ((R >> 1) & 3)) * 8));
    }
    gld16(Bt + agB0 + ko, Bq + ldsW);
    gld16(Bt + agB1 + ko, Bq + ldsW + 4096);
    __builtin_amdgcn_s_barrier();
    __builtin_amdgcn_s_setprio(1);
#pragma unroll
    for (int m = 0; m < 4; ++m)
#pragma unroll
      for (int n = 0; n < 4; ++n)
        acc[4 + m][n] = __builtin_amdgcn_mfma_f32_16x16x32_bf16(aw[m], bv[n], acc[4 + m][n], 0, 0, 0);
    __builtin_amdgcn_s_setprio(0);
    // counted drain: oldest 4 (tile t-2's loads, needed at tile t+1) retire; 8 stay in flight.
    asm volatile("s_waitcnt vmcnt(8)" ::: "memory");
    __builtin_amdgcn_s_barrier();
  }

  // epilogue: C/D layout col=lane&15, row=(lane>>4)*4+reg  [m89]
  const int crow0 = bm + wm * 128 + fg * 4;
  const int ccol0 = bn + wn * 64 + fr;
#pragma unroll
  for (int n = 0; n < 4; ++n) {
    const int col = ccol0 + n * 16;
    const float bvl = bias[col];
#pragma unroll
    for (int mf = 0; mf < 8; ++mf) {
      const int r0 = crow0 + mf * 16;
#pragma unroll
      for (int q = 0; q < 4; ++q)
        C[(size_t)(r0 + q) * 4096 + col] = acc[mf][n][q] + bvl;
    }
  }
}

extern "C" void kernel_launch(void* const* d_in, const int* in_sizes, int n_in,
                              void* d_out, int out_size, void* d_ws, size_t ws_size,
                              hipStream_t stream) {
  const float* x    = (const float*)d_in[0];
  const float* ker  = (const float*)d_in[1];
  const float* bias = (const float*)d_in[2];
  float* out = (float*)d_out;

  char* ws = (char*)d_ws;
  u16*  xb    = (u16*)ws;                      // 32 MB  bf16 x
  u16*  wt    = (u16*)(ws + 33554432);         // 32 MB  bf16 W^T
  u16*  w234t = (u16*)(ws + 67108864);         // 16 MB  bf16 W234^T
  float* w34T = (float*)(ws + 83886080);       // 512 KB fp32 W34 transposed
  // total ws use: 84,410,368 bytes

  x_to_bf16   <<<8192, 256, 0, stream>>>(x, xb);
  build_w34T  <<<512, 256, 0, stream>>>(ker, w34T);
  build_w234t2<<<512, 256, 0, stream>>>(ker, w34T, w234t);
  build_wt2   <<<1024, 256, 0, stream>>>(ker, w234t, wt);
  gemm_bt2    <<<256, 512, 0, stream>>>(xb, wt, bias, out);
}